// Round 16
// baseline (252.177 us; speedup 1.0000x reference)
//
#include <hip/hip_runtime.h>

typedef unsigned short u16;
typedef unsigned int   u32;

typedef short    short8 __attribute__((ext_vector_type(8)));
typedef __bf16   bf16x8 __attribute__((ext_vector_type(8)));
typedef _Float16 half8  __attribute__((ext_vector_type(8)));
typedef float    f32x4  __attribute__((ext_vector_type(4)));

#define S_LEN   2048
#define DM      1024
#define NHEAD   16
#define DK      64
#define KDIM    1024

// ---------- helpers ----------
__device__ __forceinline__ u16 f2bf(float f) {
    u32 u = __builtin_bit_cast(u32, f);
    u += 0x7FFFu + ((u >> 16) & 1u);      // RNE
    return (u16)(u >> 16);
}
__device__ __forceinline__ f32x4 mfma_bf16(short8 a, short8 b, f32x4 c) {
    return __builtin_amdgcn_mfma_f32_16x16x32_bf16(
        __builtin_bit_cast(bf16x8, a), __builtin_bit_cast(bf16x8, b), c, 0, 0, 0);
}
__device__ __forceinline__ f32x4 mfma_f16(half8 a, half8 b, f32x4 c) {
    return __builtin_amdgcn_mfma_f32_16x16x32_f16(a, b, c, 0, 0, 0);
}
__device__ __forceinline__ u32 pk_f16(float a, float b) {
    return __builtin_bit_cast(u32, __builtin_amdgcn_cvt_pkrtz(a, b));
}
__device__ __forceinline__ void gl_lds16(const void* g, void* l) {
    __builtin_amdgcn_global_load_lds(
        (const __attribute__((address_space(1))) u32*)g,
        (__attribute__((address_space(3))) u32*)l, 16, 0, 0);
}
// raw barrier / waitcnt (flash only): prefetch stays in flight across barrier
__device__ __forceinline__ void bar_raw() { asm volatile("s_barrier" ::: "memory"); }
__device__ __forceinline__ void wait_vm2() { asm volatile("s_waitcnt vmcnt(2)" ::: "memory"); }
__device__ __forceinline__ void wait_vm0() { asm volatile("s_waitcnt vmcnt(0)" ::: "memory"); }

// K-row permutation for flash: LDS row rc holds global k-row perm_inv(rc) so that
// PV A-frags are in-lane after S^T: k'(nt,quad,r)=32*(nt>>1)+8*quad+4*(nt&1)+r
__device__ __forceinline__ int perm_inv(int rc) {
    const int nt = rc >> 4, mid = (rc >> 2) & 3, r = rc & 3;
    return 32 * (nt >> 1) + 8 * mid + 4 * (nt & 1) + r;
}

// ---------- fused fp32->bf16 convert + RoPE table build ----------
__global__ void cvt_all(const float4* __restrict__ x,  const float4* __restrict__ Wq,
                        const float4* __restrict__ Wk, const float4* __restrict__ Wv,
                        const float4* __restrict__ Wo,
                        uint2* __restrict__ oX, uint2* __restrict__ oWcat,
                        uint2* __restrict__ oWo,
                        float* __restrict__ sT, float* __restrict__ cT) {
    const int i = blockIdx.x * 256 + threadIdx.x;
    if (i < 3145728) {
        const float4* in;
        uint2* out;
        if (i < 2097152) {
            in = x + i;  out = oX + i;
        } else {
            const int j = i - 2097152;
            const int w = j >> 18, k = j & 262143;
            in  = (w == 0 ? Wq : w == 1 ? Wk : w == 2 ? Wv : Wo) + k;
            out = (w < 3) ? (oWcat + w * 262144 + k) : (oWo + k);
        }
        float4 f = *in;
        uint2 o;
        o.x = (u32)f2bf(f.x) | ((u32)f2bf(f.y) << 16);
        o.y = (u32)f2bf(f.z) | ((u32)f2bf(f.w) << 16);
        *out = o;
    } else {
        const int idx = i - 3145728;            // [0, 65536): i=idx>>11, s=idx&2047
        const float fi = expf(-(float)(idx >> 11) * 0.287823136624255f);
        const float ang = (float)(idx & 2047) * fi;
        sT[idx] = sinf(ang);
        cT[idx] = cosf(ang);
    }
}

// ---------- NT GEMM, m97-exact structure (banked 89.1us): BM=BN=128, BK=64 ----------
// Single-buffered 32KB LDS, __syncthreads pair (compiler emits vmcnt(0) drain),
// 32 MFMA per barrier-pair, cross-block TLP provides the overlap (m114).
// BK=64 as TWO 32-col sub-tiles, each with R2's conflict-free XOR chunk swizzle.
// K=1024 shape pins the 128^2 family at ~570 TF — GEMM lever exhausted (R2-R8).
// T1 XCD remap kept. MODE 0: QKV+RoPE epilogue; MODE 1: fp32 store.
template <int MODE>
__global__ __launch_bounds__(256)
void gemm_nt(const u16* __restrict__ A, const u16* __restrict__ Bw,
             u16* __restrict__ oQ, u16* __restrict__ oK, u16* __restrict__ oVt,
             float* __restrict__ oF,
             const float* __restrict__ ropeS, const float* __restrict__ ropeC) {
    __shared__ u16 As[2][128 * 32];   // [k-slice][128 rows x 32 cols], single-buffered
    __shared__ u16 Bs[2][128 * 32];
    const int tid  = threadIdx.x;
    const int wave = tid >> 6, lane = tid & 63;
    const int quad = lane >> 4, l15 = lane & 15;
    const int wr = wave >> 1, wc = wave & 1;
    // T1 remap: lin -> (xcd, idx); y = xcd*8 + idx/NX, x = idx%NX
    const int NX  = (MODE == 0) ? 24 : 8;
    const int lin = (int)blockIdx.x + NX * (int)blockIdx.y;
    const int xcd = lin & 7, idx = lin >> 3;
    const int mbase = (xcd * 8 + idx / NX) * 128;
    const int nbase = (idx % NX) * 128;

    f32x4 acc[4][4];
#pragma unroll
    for (int i = 0; i < 4; i++)
#pragma unroll
        for (int j = 0; j < 4; j++) acc[i][j] = (f32x4)0.0f;

    // staging (per 32-col sub-tile, R2-proven): physical chunk (lane&3) of row srow
    // holds global chunk (lane&3)^((srow>>1)&3); 2 row-blocks (srow, srow+16)/call pair
    const int srow0 = wave * 32 + (lane >> 2);
    const int srow1 = srow0 + 16;
    const int scolb = ((lane & 3) ^ ((lane >> 3) & 3)) * 16;   // bytes within 64B subrow
    const int ldsOff = wave * 2048 + lane * 16;                // bytes
    const u16* gA0 = A  + (size_t)(mbase + srow0) * KDIM;
    const u16* gA1 = A  + (size_t)(mbase + srow1) * KDIM;
    const u16* gB0 = Bw + (size_t)(nbase + srow0) * KDIM;
    const u16* gB1 = Bw + (size_t)(nbase + srow1) * KDIM;
    // fragment read: chunk quad of row R at physical chunk quad^((l15>>1)&3)
    const int koffq = (quad ^ ((l15 >> 1) & 3)) * 8;    // u16 units

    const int KT = KDIM / 64;   // 16 K-steps
    for (int kt = 0; kt < KT; kt++) {
        const int kk = kt * 64;
        __syncthreads();   // all waves done reading previous tile's LDS
#pragma unroll
        for (int s = 0; s < 2; s++) {
            const int ko = kk + s * 32;
            gl_lds16((const char*)(gA0 + ko) + scolb, (char*)As[s] + ldsOff);
            gl_lds16((const char*)(gA1 + ko) + scolb, (char*)As[s] + ldsOff + 1024);
            gl_lds16((const char*)(gB0 + ko) + scolb, (char*)Bs[s] + ldsOff);
            gl_lds16((const char*)(gB1 + ko) + scolb, (char*)Bs[s] + ldsOff + 1024);
        }
        __syncthreads();   // compiler emits s_waitcnt vmcnt(0) drain before s_barrier

        short8 af[4][2], bf[4][2];
#pragma unroll
        for (int s = 0; s < 2; s++) {
#pragma unroll
            for (int mt = 0; mt < 4; mt++)
                af[mt][s] = *(const short8*)&As[s][(wr * 64 + mt * 16 + l15) * 32 + koffq];
#pragma unroll
            for (int nt = 0; nt < 4; nt++)
                bf[nt][s] = *(const short8*)&Bs[s][(wc * 64 + nt * 16 + l15) * 32 + koffq];
        }
#pragma unroll
        for (int s = 0; s < 2; s++)
#pragma unroll
            for (int mt = 0; mt < 4; mt++)
#pragma unroll
                for (int nt = 0; nt < 4; nt++)
                    acc[mt][nt] = mfma_bf16(af[mt][s], bf[nt][s], acc[mt][nt]);
    }

    // ---- epilogue. C layout: col = l15, row = quad*4 + reg ----
    const int proj_blk = (MODE == 0) ? (nbase >> 10) : 2;   // block-uniform: 0=Q 1=K 2=V

    const float* sB[4];
    const float* cB[4];
    if (MODE == 0 && proj_blk < 2) {
#pragma unroll
        for (int nt = 0; nt < 4; nt++) {
            const int fi = nt * 8 + (l15 >> 1);
            sB[nt] = ropeS + fi * 2048;
            cB[nt] = ropeC + fi * 2048;
        }
    }
    const int par = l15 & 1;   // 0: even d (e-slot), 1: odd d (o-slot)

#pragma unroll
    for (int mt = 0; mt < 4; mt++) {
#pragma unroll
        for (int nt = 0; nt < 4; nt++) {
            const int n  = nbase + wc * 64 + nt * 16 + l15;
            const int mb = mbase + wr * 64 + mt * 16 + quad * 4;
            f32x4 v = acc[mt][nt];
            if (MODE == 0) {
                const int e = n & 1023;
                const int h = e >> 6, d = e & 63;
                if (proj_blk == 2) {
                    const int b_ = mb >> 11, s = mb & 2047;
                    const int bh = b_ * NHEAD + h;
                    uint2 pk;                           // fp16 V (RTZ)
                    pk.x = pk_f16(v[0], v[1]);
                    pk.y = pk_f16(v[2], v[3]);
                    *(uint2*)&oVt[((size_t)bh * DK + d) * S_LEN + s] = pk;
                } else {
                    u16* dst = (proj_blk == 0) ? oQ : oK;
                    // partner values (d^1 lives in lane^1)
                    float vp[4];
#pragma unroll
                    for (int r = 0; r < 4; r++) vp[r] = __shfl_xor(v[r], 1);
                    const int b_ = mb >> 11, s0 = mb & 2047;
                    const int bh = b_ * NHEAD + h;
                    const f32x4 sn = *(const f32x4*)(sB[nt] + s0);   // s0 % 4 == 0
                    const f32x4 cs = *(const f32x4*)(cB[nt] + s0);
#pragma unroll
                    for (int r = 0; r < 4; r++) {
                        const float res = par ? (vp[r] * sn[r] + v[r] * cs[r])
                                              : (v[r] * cs[r] - vp[r] * sn[r]);
                        dst[((size_t)bh * S_LEN + (s0 + r)) * DK + d] = f2bf(res);
                    }
                }
            } else {
#pragma unroll
                for (int r = 0; r < 4; r++)
                    oF[(size_t)(mb + r) * DM + n] = v[r];
            }
        }
    }
}

// ---------- causal flash attention: R15b — complementary-qt pairing, 512 blocks ----------
// R15 post-mortem: 1-barrier/3-buf was neutral -> sync-frequency exhausted. Remaining
// identified inefficiency: LOAD IMBALANCE. Per-block work NT=2qt+2 spans 2..32 (16x);
// with ~2 blocks/CU resident the heavy qt=15 blocks define a tail greedy refill can't
// fully fill. Fix: block p (of 8) processes qt=15-p THEN qt=p sequentially ->
// NT(15-p)+NT(p) = (32-2p)+(2p+2) = 34 tile-iters for EVERY block. 512 blocks =
// exactly 2/CU, all co-resident at launch: zero dispatch tail, zero rebalancing
// dependence. Between passes: bar_raw (pass-B staging must not overwrite LDS a
// lagging wave still reads); pass-A's final vmcnt(0) already drained its loads.
// Per-(row,kt) math unchanged -> bitwise-identical output.
// Kept: 8-wave half-split, 1-barrier/3-buf pipeline, T13 defer-max + SCL fold,
// T1 XCD remap, T5 setprio.
__global__ __launch_bounds__(512)
void flash_attn(const u16* __restrict__ Q, const u16* __restrict__ K,
                const u16* __restrict__ Vt, u16* __restrict__ Oc) {
    __shared__ u16 Ks[3][64 * 64];     // permuted k-rows, XOR chunk swizzle
    __shared__ u16 Vs[3][64 * 64];     // [d][s], XOR chunk swizzle
    const int lin = (int)blockIdx.x + 64 * (int)blockIdx.y;   // [0,512)
    const int xcd = lin & 7, idx = lin >> 3;                  // idx in [0,64)
    const int bh  = xcd * 8 + (idx & 7);
    const int p   = idx >> 3;                                 // pair index [0,8)
    const int tid  = threadIdx.x;
    const int wave = tid >> 6, lane = tid & 63;
    const int hh   = wave >> 2, w4 = wave & 3;   // half, chain-within-half
    const int quad = lane >> 4, l15 = lane & 15;
    const int x7 = l15 & 7;
    const size_t headQK = (size_t)bh * S_LEN * DK;
    const size_t headVt = (size_t)bh * DK * S_LEN;
    const int b = bh >> 4, h = bh & 15;
    const float SCL = 0.18033688011112042f;   // (1/8) * log2(e)
    const float THRESH = 44.3614195558365f;   // 8 / SCL (defer-max, log2 bound 8)

    half8 ones;
#pragma unroll
    for (int j = 0; j < 8; j++) ones[j] = (_Float16)1.0f;

    // staging: 8 waves x 8 rows; rows rc = wave*8 + (lane>>3), chunk (lane&7)^rwl
    const int rwl  = lane >> 3;                 // row within 8-row slab
    const int scol = (lane & 7) ^ rwl;          // XOR-swizzled chunk column
    const int rc   = wave * 8 + rwl;
    const u16* gK = K  + headQK + (size_t)perm_inv(rc) * DK + scol * 8;
    const u16* gV = Vt + headVt + (size_t)rc * S_LEN + scol * 8;
    const int ldsOff = wave * 1024 + lane * 16;
    const int koff0 = (quad ^ x7) * 8;          // dk chunk 0..31, swizzled
    const int koff1 = ((4 + quad) ^ x7) * 8;    // dk chunk 32..63

    for (int pass = 0; pass < 2; pass++) {
        const int qt = pass ? p : (15 - p);     // heavy tile first
        // Q B-fragments (one 16-row chain per wave)
        short8 qf0, qf1;
        {
            const int qrow = qt * 128 + hh * 64 + w4 * 16 + l15;
            qf0 = *(const short8*)&Q[headQK + (size_t)qrow * DK + quad * 8];
            qf1 = *(const short8*)&Q[headQK + (size_t)qrow * DK + 32 + quad * 8];
        }

        float m_st = -__builtin_inff();
        f32x4 lacc = (f32x4)0.0f;
        f32x4 oacc[4];
#pragma unroll
        for (int n = 0; n < 4; n++) oacc[n] = (f32x4)0.0f;

        const int NT = 2 * qt + 2;                  // >= 2
        const int skip_kt = (hh == 0) ? (2 * qt + 1) : -1;   // fully masked for half 0
        const int diag_kt = 2 * qt + hh;

        bar_raw();   // pass B: all waves done reading pass A's LDS (no-op cost pass A)
        // prologue: stage tiles 0,1 into buffers 0,1 (2 loads per wave each)
        gl_lds16(gK, (char*)Ks[0] + ldsOff);
        gl_lds16(gV, (char*)Vs[0] + ldsOff);
        gl_lds16(gK + (size_t)64 * DK, (char*)Ks[1] + ldsOff);
        gl_lds16(gV + 64,              (char*)Vs[1] + ldsOff);

        int cur = 0, stg = 2;                       // cur = kt%3, stg = (kt+2)%3
        for (int kt = 0; kt < NT; kt++) {
            if (kt + 1 < NT) wait_vm2(); else wait_vm0();   // tile kt retired per-wave
            bar_raw();   // kt visible to all; all waves done computing kt-1
            if (kt + 2 < NT) {   // stage kt+2 (issued before compute -> latency hidden)
                gl_lds16(gK + (size_t)(kt + 2) * 64 * DK, (char*)Ks[stg] + ldsOff);
                gl_lds16(gV + (size_t)(kt + 2) * 64,      (char*)Vs[stg] + ldsOff);
            }

            if (kt != skip_kt) {   // wave-uniform; half-0 skips its fully-masked tile
                // ---- QK^T (scores RAW; SCL folded into exp2) ----
                f32x4 sc[4];
                __builtin_amdgcn_s_setprio(1);
#pragma unroll
                for (int nt = 0; nt < 4; nt++) {
                    const int rb = (nt * 16 + l15) * 64;
                    short8 kf0 = *(const short8*)&Ks[cur][rb + koff0];
                    short8 kf1 = *(const short8*)&Ks[cur][rb + koff1];
                    f32x4 z = (f32x4)0.0f;
                    z = mfma_bf16(kf0, qf0, z);
                    z = mfma_bf16(kf1, qf1, z);
                    sc[nt] = z;
                }
                __builtin_amdgcn_s_setprio(0);

                if (kt == diag_kt) {   // diagonal tile: local k' > w4*16 + l15
                    const int qloc = w4 * 16 + l15;
#pragma unroll
                    for (int nt = 0; nt < 4; nt++) {
                        const int kb = 32 * (nt >> 1) + 8 * quad + 4 * (nt & 1);
#pragma unroll
                        for (int r = 0; r < 4; r++)
                            if (kb + r > qloc) sc[nt][r] = -__builtin_inff();
                    }
                }
                // row max (max3-fusable associativity; exact)
                float mx0 = fmaxf(fmaxf(fmaxf(sc[0][0], sc[0][1]), sc[0][2]), sc[0][3]);
                float mx1 = fmaxf(fmaxf(fmaxf(sc[1][0], sc[1][1]), sc[1][2]), sc[1][3]);
                float mx2 = fmaxf(fmaxf(fmaxf(sc[2][0], sc[2][1]), sc[2][2]), sc[2][3]);
                float mx3 = fmaxf(fmaxf(fmaxf(sc[3][0], sc[3][1]), sc[3][2]), sc[3][3]);
                float mx = fmaxf(fmaxf(fmaxf(mx0, mx1), mx2), mx3);
                mx = fmaxf(mx, __shfl_xor(mx, 16));
                mx = fmaxf(mx, __shfl_xor(mx, 32));
                // T13 defer-max: rescale only when some row's max grew past THRESH
                if (!__all(mx - m_st <= THRESH)) {
                    const float mn = fmaxf(m_st, mx);
                    const float alpha = __builtin_amdgcn_exp2f((m_st - mn) * SCL);
                    m_st = mn;
                    float alr[4];
#pragma unroll
                    for (int r = 0; r < 4; r++) alr[r] = __shfl(alpha, quad * 20 + r);
#pragma unroll
                    for (int n = 0; n < 4; n++)
#pragma unroll
                        for (int r = 0; r < 4; r++) oacc[n][r] *= alr[r];
#pragma unroll
                    for (int r = 0; r < 4; r++) lacc[r] *= alr[r];
                }
                // P = exp2(fma(sc, SCL, -m*SCL)); bounded by 2^8 when deferred
                const float msc = m_st * SCL;
#pragma unroll
                for (int nt = 0; nt < 4; nt++)
#pragma unroll
                    for (int r = 0; r < 4; r++)
                        sc[nt][r] = __builtin_amdgcn_exp2f(
                            __builtin_fmaf(sc[nt][r], SCL, -msc));
                u32 pw[8];
                pw[0] = pk_f16(sc[0][0], sc[0][1]); pw[1] = pk_f16(sc[0][2], sc[0][3]);
                pw[2] = pk_f16(sc[1][0], sc[1][1]); pw[3] = pk_f16(sc[1][2], sc[1][3]);
                pw[4] = pk_f16(sc[2][0], sc[2][1]); pw[5] = pk_f16(sc[2][2], sc[2][3]);
                pw[6] = pk_f16(sc[3][0], sc[3][1]); pw[7] = pk_f16(sc[3][2], sc[3][3]);
                half8 pf0 = __builtin_bit_cast(half8, *(uint4*)&pw[0]);
                half8 pf1 = __builtin_bit_cast(half8, *(uint4*)&pw[4]);

                // ---- PV + row-sum (fp16) ----
                __builtin_amdgcn_s_setprio(1);
#pragma unroll
                for (int c = 0; c < 2; c++) {
                    const half8 pf = c ? pf1 : pf0;
                    lacc = mfma_f16(pf, ones, lacc);
                    const int voff = ((c * 4 + quad) ^ x7) * 8;
#pragma unroll
                    for (int nt2 = 0; nt2 < 4; nt2++) {
                        half8 vf = __builtin_bit_cast(half8,
                            *(const short8*)&Vs[cur][(nt2 * 16 + l15) * 64 + voff]);
                        oacc[nt2] = mfma_f16(pf, vf, oacc[nt2]);
                    }
                }
                __builtin_amdgcn_s_setprio(0);
            }

            cur = (cur == 2) ? 0 : cur + 1;
            stg = (stg == 2) ? 0 : stg + 1;
        }
        // all loads retired by the final iter's wait_vm0; no dangling prefetch

        // epilogue: rows quad*4+r, cols l15
#pragma unroll
        for (int r = 0; r < 4; r++) {
            const float inv = 1.0f / lacc[r];
            const int s = qt * 128 + hh * 64 + w4 * 16 + quad * 4 + r;
#pragma unroll
            for (int nt2 = 0; nt2 < 4; nt2++)
                Oc[((size_t)(b * S_LEN + s)) * DM + h * 64 + nt2 * 16 + l15] =
                    f2bf(oacc[nt2][r] * inv);
        }
    }
}

// ---------- workspace layout (u16 elements) ----------
#define OFF_XBF   ((size_t)0)
#define OFF_WCAT  ((size_t)8388608)
#define OFF_WO    ((size_t)11534336)
#define OFF_QB    ((size_t)12582912)
#define OFF_KB    ((size_t)20971520)
#define OFF_VT    ((size_t)29360128)
#define OFF_ROPE  ((size_t)37748736)   // 65536 fp32 sin + 65536 fp32 cos = 512 KB

extern "C" void kernel_launch(void* const* d_in, const int* in_sizes, int n_in,
                              void* d_out, int out_size, void* d_ws, size_t ws_size,
                              hipStream_t stream) {
    const float* x  = (const float*)d_in[0];
    const float* Wq = (const float*)d_in[1];
    const float* Wk = (const float*)d_in[2];
    const float* Wv = (const float*)d_in[3];
    const float* Wo = (const float*)d_in[4];
    u16* ws  = (u16*)d_ws;
    u16* XBF = ws + OFF_XBF;
    u16* WCA = ws + OFF_WCAT;
    u16* WOB = ws + OFF_WO;
    u16* QB  = ws + OFF_QB;
    u16* KB  = ws + OFF_KB;
    u16* VT  = ws + OFF_VT;
    float* ropeS = (float*)(ws + OFF_ROPE);
    float* ropeC = ropeS + 65536;
    u16* AT  = XBF;   // reuse

    cvt_all<<<12544, 256, 0, stream>>>((const float4*)x, (const float4*)Wq,
                                       (const float4*)Wk, (const float4*)Wv,
                                       (const float4*)Wo,
                                       (uint2*)XBF, (uint2*)WCA, (uint2*)WOB,
                                       ropeS, ropeC);

    gemm_nt<0><<<dim3(24, 64), 256, 0, stream>>>(XBF, WCA, QB, KB, VT, nullptr,
                                                 ropeS, ropeC);
    flash_attn<<<dim3(64, 8), 512, 0, stream>>>(QB, KB, VT, AT);
    gemm_nt<1><<<dim3(8, 64), 256, 0, stream>>>(AT, WOB, nullptr, nullptr, nullptr,
                                                (float*)d_out, nullptr, nullptr);
}

// Round 18
// 247.227 us; speedup vs baseline: 1.0200x; 1.0200x over previous
//
#include <hip/hip_runtime.h>

typedef unsigned short u16;
typedef unsigned int   u32;

typedef short    short8 __attribute__((ext_vector_type(8)));
typedef __bf16   bf16x8 __attribute__((ext_vector_type(8)));
typedef _Float16 half8  __attribute__((ext_vector_type(8)));
typedef float    f32x4  __attribute__((ext_vector_type(4)));

#define S_LEN   2048
#define DM      1024
#define NHEAD   16
#define DK      64
#define KDIM    1024

// ---------- helpers ----------
__device__ __forceinline__ u16 f2bf(float f) {
    u32 u = __builtin_bit_cast(u32, f);
    u += 0x7FFFu + ((u >> 16) & 1u);      // RNE
    return (u16)(u >> 16);
}
__device__ __forceinline__ f32x4 mfma_bf16(short8 a, short8 b, f32x4 c) {
    return __builtin_amdgcn_mfma_f32_16x16x32_bf16(
        __builtin_bit_cast(bf16x8, a), __builtin_bit_cast(bf16x8, b), c, 0, 0, 0);
}
__device__ __forceinline__ f32x4 mfma_f16(half8 a, half8 b, f32x4 c) {
    return __builtin_amdgcn_mfma_f32_16x16x32_f16(a, b, c, 0, 0, 0);
}
__device__ __forceinline__ u32 pk_f16(float a, float b) {
    return __builtin_bit_cast(u32, __builtin_amdgcn_cvt_pkrtz(a, b));
}
__device__ __forceinline__ void gl_lds16(const void* g, void* l) {
    __builtin_amdgcn_global_load_lds(
        (const __attribute__((address_space(1))) u32*)g,
        (__attribute__((address_space(3))) u32*)l, 16, 0, 0);
}
// raw barrier / waitcnt (flash only): prefetch stays in flight across barrier
__device__ __forceinline__ void bar_raw() { asm volatile("s_barrier" ::: "memory"); }
__device__ __forceinline__ void wait_vm2() { asm volatile("s_waitcnt vmcnt(2)" ::: "memory"); }
__device__ __forceinline__ void wait_vm0() { asm volatile("s_waitcnt vmcnt(0)" ::: "memory"); }

// K-row permutation for flash: LDS row rc holds global k-row perm_inv(rc) so that
// PV A-frags are in-lane after S^T: k'(nt,quad,r)=32*(nt>>1)+8*quad+4*(nt&1)+r
__device__ __forceinline__ int perm_inv(int rc) {
    const int nt = rc >> 4, mid = (rc >> 2) & 3, r = rc & 3;
    return 32 * (nt >> 1) + 8 * mid + 4 * (nt & 1) + r;
}

// ---------- fused fp32->bf16 convert + RoPE table build ----------
__global__ void cvt_all(const float4* __restrict__ x,  const float4* __restrict__ Wq,
                        const float4* __restrict__ Wk, const float4* __restrict__ Wv,
                        const float4* __restrict__ Wo,
                        uint2* __restrict__ oX, uint2* __restrict__ oWcat,
                        uint2* __restrict__ oWo,
                        float* __restrict__ sT, float* __restrict__ cT) {
    const int i = blockIdx.x * 256 + threadIdx.x;
    if (i < 3145728) {
        const float4* in;
        uint2* out;
        if (i < 2097152) {
            in = x + i;  out = oX + i;
        } else {
            const int j = i - 2097152;
            const int w = j >> 18, k = j & 262143;
            in  = (w == 0 ? Wq : w == 1 ? Wk : w == 2 ? Wv : Wo) + k;
            out = (w < 3) ? (oWcat + w * 262144 + k) : (oWo + k);
        }
        float4 f = *in;
        uint2 o;
        o.x = (u32)f2bf(f.x) | ((u32)f2bf(f.y) << 16);
        o.y = (u32)f2bf(f.z) | ((u32)f2bf(f.w) << 16);
        *out = o;
    } else {
        const int idx = i - 3145728;            // [0, 65536): i=idx>>11, s=idx&2047
        const float fi = expf(-(float)(idx >> 11) * 0.287823136624255f);
        const float ang = (float)(idx & 2047) * fi;
        sT[idx] = sinf(ang);
        cT[idx] = cosf(ang);
    }
}

// ---------- NT GEMM, m97-exact structure (banked ~88us): BM=BN=128, BK=64 ----------
// Single-buffered 32KB LDS, __syncthreads pair (compiler emits vmcnt(0) drain),
// 32 MFMA per barrier-pair, cross-block TLP provides the overlap (m114).
// BK=64 as TWO 32-col sub-tiles, each with R2's conflict-free XOR chunk swizzle.
// K=1024 shape pins the 128^2 family at ~570 TF — GEMM lever exhausted (R2-R8).
// T1 XCD remap kept. MODE 0: QKV+RoPE epilogue; MODE 1: fp32 store.
template <int MODE>
__global__ __launch_bounds__(256)
void gemm_nt(const u16* __restrict__ A, const u16* __restrict__ Bw,
             u16* __restrict__ oQ, u16* __restrict__ oK, u16* __restrict__ oVt,
             float* __restrict__ oF,
             const float* __restrict__ ropeS, const float* __restrict__ ropeC) {
    __shared__ u16 As[2][128 * 32];   // [k-slice][128 rows x 32 cols], single-buffered
    __shared__ u16 Bs[2][128 * 32];
    const int tid  = threadIdx.x;
    const int wave = tid >> 6, lane = tid & 63;
    const int quad = lane >> 4, l15 = lane & 15;
    const int wr = wave >> 1, wc = wave & 1;
    // T1 remap: lin -> (xcd, idx); y = xcd*8 + idx/NX, x = idx%NX
    const int NX  = (MODE == 0) ? 24 : 8;
    const int lin = (int)blockIdx.x + NX * (int)blockIdx.y;
    const int xcd = lin & 7, idx = lin >> 3;
    const int mbase = (xcd * 8 + idx / NX) * 128;
    const int nbase = (idx % NX) * 128;

    f32x4 acc[4][4];
#pragma unroll
    for (int i = 0; i < 4; i++)
#pragma unroll
        for (int j = 0; j < 4; j++) acc[i][j] = (f32x4)0.0f;

    // staging (per 32-col sub-tile, R2-proven): physical chunk (lane&3) of row srow
    // holds global chunk (lane&3)^((srow>>1)&3); 2 row-blocks (srow, srow+16)/call pair
    const int srow0 = wave * 32 + (lane >> 2);
    const int srow1 = srow0 + 16;
    const int scolb = ((lane & 3) ^ ((lane >> 3) & 3)) * 16;   // bytes within 64B subrow
    const int ldsOff = wave * 2048 + lane * 16;                // bytes
    const u16* gA0 = A  + (size_t)(mbase + srow0) * KDIM;
    const u16* gA1 = A  + (size_t)(mbase + srow1) * KDIM;
    const u16* gB0 = Bw + (size_t)(nbase + srow0) * KDIM;
    const u16* gB1 = Bw + (size_t)(nbase + srow1) * KDIM;
    // fragment read: chunk quad of row R at physical chunk quad^((l15>>1)&3)
    const int koffq = (quad ^ ((l15 >> 1) & 3)) * 8;    // u16 units

    const int KT = KDIM / 64;   // 16 K-steps
    for (int kt = 0; kt < KT; kt++) {
        const int kk = kt * 64;
        __syncthreads();   // all waves done reading previous tile's LDS
#pragma unroll
        for (int s = 0; s < 2; s++) {
            const int ko = kk + s * 32;
            gl_lds16((const char*)(gA0 + ko) + scolb, (char*)As[s] + ldsOff);
            gl_lds16((const char*)(gA1 + ko) + scolb, (char*)As[s] + ldsOff + 1024);
            gl_lds16((const char*)(gB0 + ko) + scolb, (char*)Bs[s] + ldsOff);
            gl_lds16((const char*)(gB1 + ko) + scolb, (char*)Bs[s] + ldsOff + 1024);
        }
        __syncthreads();   // compiler emits s_waitcnt vmcnt(0) drain before s_barrier

        short8 af[4][2], bf[4][2];
#pragma unroll
        for (int s = 0; s < 2; s++) {
#pragma unroll
            for (int mt = 0; mt < 4; mt++)
                af[mt][s] = *(const short8*)&As[s][(wr * 64 + mt * 16 + l15) * 32 + koffq];
#pragma unroll
            for (int nt = 0; nt < 4; nt++)
                bf[nt][s] = *(const short8*)&Bs[s][(wc * 64 + nt * 16 + l15) * 32 + koffq];
        }
#pragma unroll
        for (int s = 0; s < 2; s++)
#pragma unroll
            for (int mt = 0; mt < 4; mt++)
#pragma unroll
                for (int nt = 0; nt < 4; nt++)
                    acc[mt][nt] = mfma_bf16(af[mt][s], bf[nt][s], acc[mt][nt]);
    }

    // ---- epilogue. C layout: col = l15, row = quad*4 + reg ----
    const int proj_blk = (MODE == 0) ? (nbase >> 10) : 2;   // block-uniform: 0=Q 1=K 2=V

    const float* sB[4];
    const float* cB[4];
    if (MODE == 0 && proj_blk < 2) {
#pragma unroll
        for (int nt = 0; nt < 4; nt++) {
            const int fi = nt * 8 + (l15 >> 1);
            sB[nt] = ropeS + fi * 2048;
            cB[nt] = ropeC + fi * 2048;
        }
    }
    const int par = l15 & 1;   // 0: even d (e-slot), 1: odd d (o-slot)

#pragma unroll
    for (int mt = 0; mt < 4; mt++) {
#pragma unroll
        for (int nt = 0; nt < 4; nt++) {
            const int n  = nbase + wc * 64 + nt * 16 + l15;
            const int mb = mbase + wr * 64 + mt * 16 + quad * 4;
            f32x4 v = acc[mt][nt];
            if (MODE == 0) {
                const int e = n & 1023;
                const int h = e >> 6, d = e & 63;
                if (proj_blk == 2) {
                    const int b_ = mb >> 11, s = mb & 2047;
                    const int bh = b_ * NHEAD + h;
                    uint2 pk;                           // fp16 V (RTZ)
                    pk.x = pk_f16(v[0], v[1]);
                    pk.y = pk_f16(v[2], v[3]);
                    *(uint2*)&oVt[((size_t)bh * DK + d) * S_LEN + s] = pk;
                } else {
                    u16* dst = (proj_blk == 0) ? oQ : oK;
                    // partner values (d^1 lives in lane^1)
                    float vp[4];
#pragma unroll
                    for (int r = 0; r < 4; r++) vp[r] = __shfl_xor(v[r], 1);
                    const int b_ = mb >> 11, s0 = mb & 2047;
                    const int bh = b_ * NHEAD + h;
                    const f32x4 sn = *(const f32x4*)(sB[nt] + s0);   // s0 % 4 == 0
                    const f32x4 cs = *(const f32x4*)(cB[nt] + s0);
#pragma unroll
                    for (int r = 0; r < 4; r++) {
                        const float res = par ? (vp[r] * sn[r] + v[r] * cs[r])
                                              : (v[r] * cs[r] - vp[r] * sn[r]);
                        dst[((size_t)bh * S_LEN + (s0 + r)) * DK + d] = f2bf(res);
                    }
                }
            } else {
#pragma unroll
                for (int r = 0; r < 4; r++)
                    oF[(size_t)(mb + r) * DM + n] = v[r];
            }
        }
    }
}

// ---------- causal flash attention: R13 (session best, 245.8us total) ----------
// 8 waves x 512 threads per 128-row block; waves 0-3 run half-0's four 16-row
// chains, waves 4-7 half-1's. Per-wave state = single chain (TLP/VGPR win from
// R12, +17us) with K/V staged ONCE per 128 q-rows (R13 recombine, +11us).
// Each wave stages 8 rows of K and V per tile (1+1 gl_lds16, ldsOff=wave*1024);
// counted wait vmcnt(2); raw-barrier dist-1 double-buffer. Half-0 waves skip the
// fully-masked kt==2qt+1 compute (uniform per wave; barriers still hit).
// R15/R16 lessons: 1-barrier/3-buf = neutral; complementary-qt pairing = -6us.
// This config is the measured floor of the flash schedule family.
// T13 defer-max + SCL fold, T1 XCD remap, T5 setprio.
__global__ __launch_bounds__(512)
void flash_attn(const u16* __restrict__ Q, const u16* __restrict__ K,
                const u16* __restrict__ Vt, u16* __restrict__ Oc) {
    __shared__ u16 Ks[2][64 * 64];     // permuted k-rows, XOR chunk swizzle
    __shared__ u16 Vs[2][64 * 64];     // [d][s], XOR chunk swizzle
    const int lin = (int)blockIdx.x + 64 * (int)blockIdx.y;   // [0,1024)
    const int xcd = lin & 7, idx = lin >> 3;                  // idx in [0,128)
    const int bh  = xcd * 8 + (idx & 7);
    const int qt  = 15 - (idx >> 3);                          // [0,16), heavy first
    const int tid  = threadIdx.x;
    const int wave = tid >> 6, lane = tid & 63;
    const int hh   = wave >> 2, w4 = wave & 3;   // half, chain-within-half
    const int quad = lane >> 4, l15 = lane & 15;
    const int x7 = l15 & 7;
    const size_t headQK = (size_t)bh * S_LEN * DK;
    const size_t headVt = (size_t)bh * DK * S_LEN;
    const int b = bh >> 4, h = bh & 15;
    const float SCL = 0.18033688011112042f;   // (1/8) * log2(e)
    const float THRESH = 44.3614195558365f;   // 8 / SCL (defer-max, log2 bound 8)

    half8 ones;
#pragma unroll
    for (int j = 0; j < 8; j++) ones[j] = (_Float16)1.0f;

    // staging: 8 waves x 8 rows; rows rc = wave*8 + (lane>>3), chunk (lane&7)^rwl
    const int rwl  = lane >> 3;                 // row within 8-row slab
    const int scol = (lane & 7) ^ rwl;          // XOR-swizzled chunk column
    const int rc   = wave * 8 + rwl;
    const u16* gK = K  + headQK + (size_t)perm_inv(rc) * DK + scol * 8;
    const u16* gV = Vt + headVt + (size_t)rc * S_LEN + scol * 8;
    const int ldsOff = wave * 1024 + lane * 16;
    const int koff0 = (quad ^ x7) * 8;          // dk chunk 0..31, swizzled
    const int koff1 = ((4 + quad) ^ x7) * 8;    // dk chunk 32..63

    // Q B-fragments (one 16-row chain per wave)
    short8 qf0, qf1;
    {
        const int qrow = qt * 128 + hh * 64 + w4 * 16 + l15;
        qf0 = *(const short8*)&Q[headQK + (size_t)qrow * DK + quad * 8];
        qf1 = *(const short8*)&Q[headQK + (size_t)qrow * DK + 32 + quad * 8];
    }

    float m_st = -__builtin_inff();
    f32x4 lacc = (f32x4)0.0f;
    f32x4 oacc[4];
#pragma unroll
    for (int n = 0; n < 4; n++) oacc[n] = (f32x4)0.0f;

    const int NT = 2 * qt + 2;
    const int skip_kt = (hh == 0) ? (2 * qt + 1) : -1;   // fully masked for half 0
    const int diag_kt = 2 * qt + hh;
    // prologue: stage tile 0 into buffer 0 (2 loads per wave)
    gl_lds16(gK, (char*)Ks[0] + ldsOff);
    gl_lds16(gV, (char*)Vs[0] + ldsOff);

    for (int kt = 0; kt < NT; kt++) {
        const int cur = kt & 1, nxt = cur ^ 1;
        bar_raw();   // (A) everyone done reading buf[nxt]
        {            // prefetch tile kt+1 (clamped dummy on last iter)
            const int ktn = (kt + 1 < NT) ? kt + 1 : kt;
            gl_lds16(gK + (size_t)ktn * 64 * DK, (char*)Ks[nxt] + ldsOff);
            gl_lds16(gV + ktn * 64,              (char*)Vs[nxt] + ldsOff);
        }
        wait_vm2();  // tile kt's 2 loads retired; prefetch stays in flight
        bar_raw();   // (B) all waves' tile-kt staging visible

        if (kt == skip_kt) continue;   // wave-uniform; barriers already passed

        // ---- QK^T (scores RAW; SCL folded into exp2) ----
        f32x4 sc[4];
        __builtin_amdgcn_s_setprio(1);
#pragma unroll
        for (int nt = 0; nt < 4; nt++) {
            const int rb = (nt * 16 + l15) * 64;
            short8 kf0 = *(const short8*)&Ks[cur][rb + koff0];
            short8 kf1 = *(const short8*)&Ks[cur][rb + koff1];
            f32x4 z = (f32x4)0.0f;
            z = mfma_bf16(kf0, qf0, z);
            z = mfma_bf16(kf1, qf1, z);
            sc[nt] = z;
        }
        __builtin_amdgcn_s_setprio(0);

        if (kt == diag_kt) {   // diagonal tile: local k' > w4*16 + l15
            const int qloc = w4 * 16 + l15;
#pragma unroll
            for (int nt = 0; nt < 4; nt++) {
                const int kb = 32 * (nt >> 1) + 8 * quad + 4 * (nt & 1);
#pragma unroll
                for (int r = 0; r < 4; r++)
                    if (kb + r > qloc) sc[nt][r] = -__builtin_inff();
            }
        }
        // row max: in-lane over 16, then across quads
        float mx0 = fmaxf(fmaxf(sc[0][0], sc[0][1]), fmaxf(sc[0][2], sc[0][3]));
        float mx1 = fmaxf(fmaxf(sc[1][0], sc[1][1]), fmaxf(sc[1][2], sc[1][3]));
        float mx2 = fmaxf(fmaxf(sc[2][0], sc[2][1]), fmaxf(sc[2][2], sc[2][3]));
        float mx3 = fmaxf(fmaxf(sc[3][0], sc[3][1]), fmaxf(sc[3][2], sc[3][3]));
        float mx = fmaxf(fmaxf(mx0, mx1), fmaxf(mx2, mx3));
        mx = fmaxf(mx, __shfl_xor(mx, 16));
        mx = fmaxf(mx, __shfl_xor(mx, 32));
        // T13 defer-max: rescale only when some row's max grew past THRESH
        if (!__all(mx - m_st <= THRESH)) {
            const float mn = fmaxf(m_st, mx);
            const float alpha = __builtin_amdgcn_exp2f((m_st - mn) * SCL);
            m_st = mn;
            float alr[4];
#pragma unroll
            for (int r = 0; r < 4; r++) alr[r] = __shfl(alpha, quad * 20 + r);
#pragma unroll
            for (int n = 0; n < 4; n++)
#pragma unroll
                for (int r = 0; r < 4; r++) oacc[n][r] *= alr[r];
#pragma unroll
            for (int r = 0; r < 4; r++) lacc[r] *= alr[r];
        }
        // P = exp2(fma(sc, SCL, -m*SCL)); bounded by 2^8 when deferred
        const float msc = m_st * SCL;
#pragma unroll
        for (int nt = 0; nt < 4; nt++)
#pragma unroll
            for (int r = 0; r < 4; r++)
                sc[nt][r] = __builtin_amdgcn_exp2f(
                    __builtin_fmaf(sc[nt][r], SCL, -msc));
        u32 pw[8];
        pw[0] = pk_f16(sc[0][0], sc[0][1]); pw[1] = pk_f16(sc[0][2], sc[0][3]);
        pw[2] = pk_f16(sc[1][0], sc[1][1]); pw[3] = pk_f16(sc[1][2], sc[1][3]);
        pw[4] = pk_f16(sc[2][0], sc[2][1]); pw[5] = pk_f16(sc[2][2], sc[2][3]);
        pw[6] = pk_f16(sc[3][0], sc[3][1]); pw[7] = pk_f16(sc[3][2], sc[3][3]);
        half8 pf0 = __builtin_bit_cast(half8, *(uint4*)&pw[0]);
        half8 pf1 = __builtin_bit_cast(half8, *(uint4*)&pw[4]);

        // ---- PV + row-sum (fp16) ----
        __builtin_amdgcn_s_setprio(1);
#pragma unroll
        for (int c = 0; c < 2; c++) {
            const half8 pf = c ? pf1 : pf0;
            lacc = mfma_f16(pf, ones, lacc);
            const int voff = ((c * 4 + quad) ^ x7) * 8;
#pragma unroll
            for (int nt2 = 0; nt2 < 4; nt2++) {
                half8 vf = __builtin_bit_cast(half8,
                    *(const short8*)&Vs[cur][(nt2 * 16 + l15) * 64 + voff]);
                oacc[nt2] = mfma_f16(pf, vf, oacc[nt2]);
            }
        }
        __builtin_amdgcn_s_setprio(0);
    }
    wait_vm0();   // drain dangling dummy prefetch before exit

    // epilogue: rows quad*4+r, cols l15
#pragma unroll
    for (int r = 0; r < 4; r++) {
        const float inv = 1.0f / lacc[r];
        const int s = qt * 128 + hh * 64 + w4 * 16 + quad * 4 + r;
#pragma unroll
        for (int nt2 = 0; nt2 < 4; nt2++)
            Oc[((size_t)(b * S_LEN + s)) * DM + h * 64 + nt2 * 16 + l15] =
                f2bf(oacc[nt2][r] * inv);
    }
}

// ---------- workspace layout (u16 elements) ----------
#define OFF_XBF   ((size_t)0)
#define OFF_WCAT  ((size_t)8388608)
#define OFF_WO    ((size_t)11534336)
#define OFF_QB    ((size_t)12582912)
#define OFF_KB    ((size_t)20971520)
#define OFF_VT    ((size_t)29360128)
#define OFF_ROPE  ((size_t)37748736)   // 65536 fp32 sin + 65536 fp32 cos = 512 KB

extern "C" void kernel_launch(void* const* d_in, const int* in_sizes, int n_in,
                              void* d_out, int out_size, void* d_ws, size_t ws_size,
                              hipStream_t stream) {
    const float* x  = (const float*)d_in[0];
    const float* Wq = (const float*)d_in[1];
    const float* Wk = (const float*)d_in[2];
    const float* Wv = (const float*)d_in[3];
    const float* Wo = (const float*)d_in[4];
    u16* ws  = (u16*)d_ws;
    u16* XBF = ws + OFF_XBF;
    u16* WCA = ws + OFF_WCAT;
    u16* WOB = ws + OFF_WO;
    u16* QB  = ws + OFF_QB;
    u16* KB  = ws + OFF_KB;
    u16* VT  = ws + OFF_VT;
    float* ropeS = (float*)(ws + OFF_ROPE);
    float* ropeC = ropeS + 65536;
    u16* AT  = XBF;   // reuse

    cvt_all<<<12544, 256, 0, stream>>>((const float4*)x, (const float4*)Wq,
                                       (const float4*)Wk, (const float4*)Wv,
                                       (const float4*)Wo,
                                       (uint2*)XBF, (uint2*)WCA, (uint2*)WOB,
                                       ropeS, ropeC);

    gemm_nt<0><<<dim3(24, 64), 256, 0, stream>>>(XBF, WCA, QB, KB, VT, nullptr,
                                                 ropeS, ropeC);
    flash_attn<<<dim3(64, 16), 512, 0, stream>>>(QB, KB, VT, AT);
    gemm_nt<1><<<dim3(8, 64), 256, 0, stream>>>(AT, WOB, nullptr, nullptr, nullptr,
                                                (float*)d_out, nullptr, nullptr);
}

// Round 20
// 245.606 us; speedup vs baseline: 1.0268x; 1.0066x over previous
//
#include <hip/hip_runtime.h>

typedef unsigned short u16;
typedef unsigned int   u32;

typedef short    short8 __attribute__((ext_vector_type(8)));
typedef __bf16   bf16x8 __attribute__((ext_vector_type(8)));
typedef _Float16 half8  __attribute__((ext_vector_type(8)));
typedef float    f32x4  __attribute__((ext_vector_type(4)));

#define S_LEN   2048
#define DM      1024
#define NHEAD   16
#define DK      64
#define KDIM    1024

// ---------- helpers ----------
__device__ __forceinline__ u16 f2bf(float f) {
    u32 u = __builtin_bit_cast(u32, f);
    u += 0x7FFFu + ((u >> 16) & 1u);      // RNE
    return (u16)(u >> 16);
}
__device__ __forceinline__ f32x4 mfma_bf16(short8 a, short8 b, f32x4 c) {
    return __builtin_amdgcn_mfma_f32_16x16x32_bf16(
        __builtin_bit_cast(bf16x8, a), __builtin_bit_cast(bf16x8, b), c, 0, 0, 0);
}
__device__ __forceinline__ f32x4 mfma_f16(half8 a, half8 b, f32x4 c) {
    return __builtin_amdgcn_mfma_f32_16x16x32_f16(a, b, c, 0, 0, 0);
}
__device__ __forceinline__ u32 pk_f16(float a, float b) {
    return __builtin_bit_cast(u32, __builtin_amdgcn_cvt_pkrtz(a, b));
}
__device__ __forceinline__ void gl_lds16(const void* g, void* l) {
    __builtin_amdgcn_global_load_lds(
        (const __attribute__((address_space(1))) u32*)g,
        (__attribute__((address_space(3))) u32*)l, 16, 0, 0);
}
// raw barrier / waitcnt (flash only): prefetch stays in flight across barrier
__device__ __forceinline__ void bar_raw() { asm volatile("s_barrier" ::: "memory"); }
__device__ __forceinline__ void wait_vm2() { asm volatile("s_waitcnt vmcnt(2)" ::: "memory"); }
__device__ __forceinline__ void wait_vm0() { asm volatile("s_waitcnt vmcnt(0)" ::: "memory"); }

// K-row permutation for flash: LDS row rc holds global k-row perm_inv(rc) so that
// PV A-frags are in-lane after S^T: k'(nt,quad,r)=32*(nt>>1)+8*quad+4*(nt&1)+r
__device__ __forceinline__ int perm_inv(int rc) {
    const int nt = rc >> 4, mid = (rc >> 2) & 3, r = rc & 3;
    return 32 * (nt >> 1) + 8 * mid + 4 * (nt & 1) + r;
}

// ---------- fused fp32->bf16 convert + RoPE table build ----------
__global__ void cvt_all(const float4* __restrict__ x,  const float4* __restrict__ Wq,
                        const float4* __restrict__ Wk, const float4* __restrict__ Wv,
                        const float4* __restrict__ Wo,
                        uint2* __restrict__ oX, uint2* __restrict__ oWcat,
                        uint2* __restrict__ oWo,
                        float* __restrict__ sT, float* __restrict__ cT) {
    const int i = blockIdx.x * 256 + threadIdx.x;
    if (i < 3145728) {
        const float4* in;
        uint2* out;
        if (i < 2097152) {
            in = x + i;  out = oX + i;
        } else {
            const int j = i - 2097152;
            const int w = j >> 18, k = j & 262143;
            in  = (w == 0 ? Wq : w == 1 ? Wk : w == 2 ? Wv : Wo) + k;
            out = (w < 3) ? (oWcat + w * 262144 + k) : (oWo + k);
        }
        float4 f = *in;
        uint2 o;
        o.x = (u32)f2bf(f.x) | ((u32)f2bf(f.y) << 16);
        o.y = (u32)f2bf(f.z) | ((u32)f2bf(f.w) << 16);
        *out = o;
    } else {
        const int idx = i - 3145728;            // [0, 65536): i=idx>>11, s=idx&2047
        const float fi = expf(-(float)(idx >> 11) * 0.287823136624255f);
        const float ang = (float)(idx & 2047) * fi;
        sT[idx] = sinf(ang);
        cT[idx] = cosf(ang);
    }
}

// ---------- NT GEMM, m97-exact structure (banked ~88us): BM=BN=128, BK=64 ----------
// Single-buffered 32KB LDS, __syncthreads pair (compiler emits vmcnt(0) drain),
// 32 MFMA per barrier-pair, cross-block TLP provides the overlap (m114).
// BK=64 as TWO 32-col sub-tiles, each with R2's conflict-free XOR chunk swizzle.
// K=1024 shape pins the 128^2 family at ~570 TF — GEMM lever exhausted (R2-R8).
// T1 XCD remap kept. MODE 0: QKV+RoPE epilogue; MODE 1: fp32 store.
template <int MODE>
__global__ __launch_bounds__(256)
void gemm_nt(const u16* __restrict__ A, const u16* __restrict__ Bw,
             u16* __restrict__ oQ, u16* __restrict__ oK, u16* __restrict__ oVt,
             float* __restrict__ oF,
             const float* __restrict__ ropeS, const float* __restrict__ ropeC) {
    __shared__ u16 As[2][128 * 32];   // [k-slice][128 rows x 32 cols], single-buffered
    __shared__ u16 Bs[2][128 * 32];
    const int tid  = threadIdx.x;
    const int wave = tid >> 6, lane = tid & 63;
    const int quad = lane >> 4, l15 = lane & 15;
    const int wr = wave >> 1, wc = wave & 1;
    // T1 remap: lin -> (xcd, idx); y = xcd*8 + idx/NX, x = idx%NX
    const int NX  = (MODE == 0) ? 24 : 8;
    const int lin = (int)blockIdx.x + NX * (int)blockIdx.y;
    const int xcd = lin & 7, idx = lin >> 3;
    const int mbase = (xcd * 8 + idx / NX) * 128;
    const int nbase = (idx % NX) * 128;

    f32x4 acc[4][4];
#pragma unroll
    for (int i = 0; i < 4; i++)
#pragma unroll
        for (int j = 0; j < 4; j++) acc[i][j] = (f32x4)0.0f;

    // staging (per 32-col sub-tile, R2-proven): physical chunk (lane&3) of row srow
    // holds global chunk (lane&3)^((srow>>1)&3); 2 row-blocks (srow, srow+16)/call pair
    const int srow0 = wave * 32 + (lane >> 2);
    const int srow1 = srow0 + 16;
    const int scolb = ((lane & 3) ^ ((lane >> 3) & 3)) * 16;   // bytes within 64B subrow
    const int ldsOff = wave * 2048 + lane * 16;                // bytes
    const u16* gA0 = A  + (size_t)(mbase + srow0) * KDIM;
    const u16* gA1 = A  + (size_t)(mbase + srow1) * KDIM;
    const u16* gB0 = Bw + (size_t)(nbase + srow0) * KDIM;
    const u16* gB1 = Bw + (size_t)(nbase + srow1) * KDIM;
    // fragment read: chunk quad of row R at physical chunk quad^((l15>>1)&3)
    const int koffq = (quad ^ ((l15 >> 1) & 3)) * 8;    // u16 units

    const int KT = KDIM / 64;   // 16 K-steps
    for (int kt = 0; kt < KT; kt++) {
        const int kk = kt * 64;
        __syncthreads();   // all waves done reading previous tile's LDS
#pragma unroll
        for (int s = 0; s < 2; s++) {
            const int ko = kk + s * 32;
            gl_lds16((const char*)(gA0 + ko) + scolb, (char*)As[s] + ldsOff);
            gl_lds16((const char*)(gA1 + ko) + scolb, (char*)As[s] + ldsOff + 1024);
            gl_lds16((const char*)(gB0 + ko) + scolb, (char*)Bs[s] + ldsOff);
            gl_lds16((const char*)(gB1 + ko) + scolb, (char*)Bs[s] + ldsOff + 1024);
        }
        __syncthreads();   // compiler emits s_waitcnt vmcnt(0) drain before s_barrier

        short8 af[4][2], bf[4][2];
#pragma unroll
        for (int s = 0; s < 2; s++) {
#pragma unroll
            for (int mt = 0; mt < 4; mt++)
                af[mt][s] = *(const short8*)&As[s][(wr * 64 + mt * 16 + l15) * 32 + koffq];
#pragma unroll
            for (int nt = 0; nt < 4; nt++)
                bf[nt][s] = *(const short8*)&Bs[s][(wc * 64 + nt * 16 + l15) * 32 + koffq];
        }
#pragma unroll
        for (int s = 0; s < 2; s++)
#pragma unroll
            for (int mt = 0; mt < 4; mt++)
#pragma unroll
                for (int nt = 0; nt < 4; nt++)
                    acc[mt][nt] = mfma_bf16(af[mt][s], bf[nt][s], acc[mt][nt]);
    }

    // ---- epilogue. C layout: col = l15, row = quad*4 + reg ----
    const int proj_blk = (MODE == 0) ? (nbase >> 10) : 2;   // block-uniform: 0=Q 1=K 2=V

    const float* sB[4];
    const float* cB[4];
    if (MODE == 0 && proj_blk < 2) {
#pragma unroll
        for (int nt = 0; nt < 4; nt++) {
            const int fi = nt * 8 + (l15 >> 1);
            sB[nt] = ropeS + fi * 2048;
            cB[nt] = ropeC + fi * 2048;
        }
    }
    const int par = l15 & 1;   // 0: even d (e-slot), 1: odd d (o-slot)

#pragma unroll
    for (int mt = 0; mt < 4; mt++) {
#pragma unroll
        for (int nt = 0; nt < 4; nt++) {
            const int n  = nbase + wc * 64 + nt * 16 + l15;
            const int mb = mbase + wr * 64 + mt * 16 + quad * 4;
            f32x4 v = acc[mt][nt];
            if (MODE == 0) {
                const int e = n & 1023;
                const int h = e >> 6, d = e & 63;
                if (proj_blk == 2) {
                    const int b_ = mb >> 11, s = mb & 2047;
                    const int bh = b_ * NHEAD + h;
                    uint2 pk;                           // fp16 V (RTZ)
                    pk.x = pk_f16(v[0], v[1]);
                    pk.y = pk_f16(v[2], v[3]);
                    *(uint2*)&oVt[((size_t)bh * DK + d) * S_LEN + s] = pk;
                } else {
                    u16* dst = (proj_blk == 0) ? oQ : oK;
                    // partner values (d^1 lives in lane^1)
                    float vp[4];
#pragma unroll
                    for (int r = 0; r < 4; r++) vp[r] = __shfl_xor(v[r], 1);
                    const int b_ = mb >> 11, s0 = mb & 2047;
                    const int bh = b_ * NHEAD + h;
                    const f32x4 sn = *(const f32x4*)(sB[nt] + s0);   // s0 % 4 == 0
                    const f32x4 cs = *(const f32x4*)(cB[nt] + s0);
#pragma unroll
                    for (int r = 0; r < 4; r++) {
                        const float res = par ? (vp[r] * sn[r] + v[r] * cs[r])
                                              : (v[r] * cs[r] - vp[r] * sn[r]);
                        dst[((size_t)bh * S_LEN + (s0 + r)) * DK + d] = f2bf(res);
                    }
                }
            } else {
#pragma unroll
                for (int r = 0; r < 4; r++)
                    oF[(size_t)(mb + r) * DM + n] = v[r];
            }
        }
    }
}

// ---------- causal flash attention: R13 (session best, 245.8/247.2us total) ----------
// 8 waves x 512 threads per 128-row block; waves 0-3 run half-0's four 16-row
// chains, waves 4-7 half-1's. Per-wave state = single chain (TLP/VGPR win from
// R12, +17us) with K/V staged ONCE per 128 q-rows (R13 recombine, +11us).
// Each wave stages 8 rows of K and V per tile (1+1 gl_lds16, ldsOff=wave*1024);
// counted wait vmcnt(2); raw-barrier dist-1 double-buffer. Half-0 waves skip the
// fully-masked kt==2qt+1 compute (uniform per wave; barriers still hit).
// R15/R16 lessons: 1-barrier/3-buf = neutral; complementary-qt pairing = -6us.
// This config is the measured floor of the flash schedule family.
// T13 defer-max + SCL fold, T1 XCD remap, T5 setprio.
__global__ __launch_bounds__(512)
void flash_attn(const u16* __restrict__ Q, const u16* __restrict__ K,
                const u16* __restrict__ Vt, u16* __restrict__ Oc) {
    __shared__ u16 Ks[2][64 * 64];     // permuted k-rows, XOR chunk swizzle
    __shared__ u16 Vs[2][64 * 64];     // [d][s], XOR chunk swizzle
    const int lin = (int)blockIdx.x + 64 * (int)blockIdx.y;   // [0,1024)
    const int xcd = lin & 7, idx = lin >> 3;                  // idx in [0,128)
    const int bh  = xcd * 8 + (idx & 7);
    const int qt  = 15 - (idx >> 3);                          // [0,16), heavy first
    const int tid  = threadIdx.x;
    const int wave = tid >> 6, lane = tid & 63;
    const int hh   = wave >> 2, w4 = wave & 3;   // half, chain-within-half
    const int quad = lane >> 4, l15 = lane & 15;
    const int x7 = l15 & 7;
    const size_t headQK = (size_t)bh * S_LEN * DK;
    const size_t headVt = (size_t)bh * DK * S_LEN;
    const int b = bh >> 4, h = bh & 15;
    const float SCL = 0.18033688011112042f;   // (1/8) * log2(e)
    const float THRESH = 44.3614195558365f;   // 8 / SCL (defer-max, log2 bound 8)

    half8 ones;
#pragma unroll
    for (int j = 0; j < 8; j++) ones[j] = (_Float16)1.0f;

    // staging: 8 waves x 8 rows; rows rc = wave*8 + (lane>>3), chunk (lane&7)^rwl
    const int rwl  = lane >> 3;                 // row within 8-row slab
    const int scol = (lane & 7) ^ rwl;          // XOR-swizzled chunk column
    const int rc   = wave * 8 + rwl;
    const u16* gK = K  + headQK + (size_t)perm_inv(rc) * DK + scol * 8;
    const u16* gV = Vt + headVt + (size_t)rc * S_LEN + scol * 8;
    const int ldsOff = wave * 1024 + lane * 16;
    const int koff0 = (quad ^ x7) * 8;          // dk chunk 0..31, swizzled
    const int koff1 = ((4 + quad) ^ x7) * 8;    // dk chunk 32..63

    // Q B-fragments (one 16-row chain per wave)
    short8 qf0, qf1;
    {
        const int qrow = qt * 128 + hh * 64 + w4 * 16 + l15;
        qf0 = *(const short8*)&Q[headQK + (size_t)qrow * DK + quad * 8];
        qf1 = *(const short8*)&Q[headQK + (size_t)qrow * DK + 32 + quad * 8];
    }

    float m_st = -__builtin_inff();
    f32x4 lacc = (f32x4)0.0f;
    f32x4 oacc[4];
#pragma unroll
    for (int n = 0; n < 4; n++) oacc[n] = (f32x4)0.0f;

    const int NT = 2 * qt + 2;
    const int skip_kt = (hh == 0) ? (2 * qt + 1) : -1;   // fully masked for half 0
    const int diag_kt = 2 * qt + hh;
    // prologue: stage tile 0 into buffer 0 (2 loads per wave)
    gl_lds16(gK, (char*)Ks[0] + ldsOff);
    gl_lds16(gV, (char*)Vs[0] + ldsOff);

    for (int kt = 0; kt < NT; kt++) {
        const int cur = kt & 1, nxt = cur ^ 1;
        bar_raw();   // (A) everyone done reading buf[nxt]
        {            // prefetch tile kt+1 (clamped dummy on last iter)
            const int ktn = (kt + 1 < NT) ? kt + 1 : kt;
            gl_lds16(gK + (size_t)ktn * 64 * DK, (char*)Ks[nxt] + ldsOff);
            gl_lds16(gV + ktn * 64,              (char*)Vs[nxt] + ldsOff);
        }
        wait_vm2();  // tile kt's 2 loads retired; prefetch stays in flight
        bar_raw();   // (B) all waves' tile-kt staging visible

        if (kt == skip_kt) continue;   // wave-uniform; barriers already passed

        // ---- QK^T (scores RAW; SCL folded into exp2) ----
        f32x4 sc[4];
        __builtin_amdgcn_s_setprio(1);
#pragma unroll
        for (int nt = 0; nt < 4; nt++) {
            const int rb = (nt * 16 + l15) * 64;
            short8 kf0 = *(const short8*)&Ks[cur][rb + koff0];
            short8 kf1 = *(const short8*)&Ks[cur][rb + koff1];
            f32x4 z = (f32x4)0.0f;
            z = mfma_bf16(kf0, qf0, z);
            z = mfma_bf16(kf1, qf1, z);
            sc[nt] = z;
        }
        __builtin_amdgcn_s_setprio(0);

        if (kt == diag_kt) {   // diagonal tile: local k' > w4*16 + l15
            const int qloc = w4 * 16 + l15;
#pragma unroll
            for (int nt = 0; nt < 4; nt++) {
                const int kb = 32 * (nt >> 1) + 8 * quad + 4 * (nt & 1);
#pragma unroll
                for (int r = 0; r < 4; r++)
                    if (kb + r > qloc) sc[nt][r] = -__builtin_inff();
            }
        }
        // row max: in-lane over 16, then across quads
        float mx0 = fmaxf(fmaxf(sc[0][0], sc[0][1]), fmaxf(sc[0][2], sc[0][3]));
        float mx1 = fmaxf(fmaxf(sc[1][0], sc[1][1]), fmaxf(sc[1][2], sc[1][3]));
        float mx2 = fmaxf(fmaxf(sc[2][0], sc[2][1]), fmaxf(sc[2][2], sc[2][3]));
        float mx3 = fmaxf(fmaxf(sc[3][0], sc[3][1]), fmaxf(sc[3][2], sc[3][3]));
        float mx = fmaxf(fmaxf(mx0, mx1), fmaxf(mx2, mx3));
        mx = fmaxf(mx, __shfl_xor(mx, 16));
        mx = fmaxf(mx, __shfl_xor(mx, 32));
        // T13 defer-max: rescale only when some row's max grew past THRESH
        if (!__all(mx - m_st <= THRESH)) {
            const float mn = fmaxf(m_st, mx);
            const float alpha = __builtin_amdgcn_exp2f((m_st - mn) * SCL);
            m_st = mn;
            float alr[4];
#pragma unroll
            for (int r = 0; r < 4; r++) alr[r] = __shfl(alpha, quad * 20 + r);
#pragma unroll
            for (int n = 0; n < 4; n++)
#pragma unroll
                for (int r = 0; r < 4; r++) oacc[n][r] *= alr[r];
#pragma unroll
            for (int r = 0; r < 4; r++) lacc[r] *= alr[r];
        }
        // P = exp2(fma(sc, SCL, -m*SCL)); bounded by 2^8 when deferred
        const float msc = m_st * SCL;
#pragma unroll
        for (int nt = 0; nt < 4; nt++)
#pragma unroll
            for (int r = 0; r < 4; r++)
                sc[nt][r] = __builtin_amdgcn_exp2f(
                    __builtin_fmaf(sc[nt][r], SCL, -msc));
        u32 pw[8];
        pw[0] = pk_f16(sc[0][0], sc[0][1]); pw[1] = pk_f16(sc[0][2], sc[0][3]);
        pw[2] = pk_f16(sc[1][0], sc[1][1]); pw[3] = pk_f16(sc[1][2], sc[1][3]);
        pw[4] = pk_f16(sc[2][0], sc[2][1]); pw[5] = pk_f16(sc[2][2], sc[2][3]);
        pw[6] = pk_f16(sc[3][0], sc[3][1]); pw[7] = pk_f16(sc[3][2], sc[3][3]);
        half8 pf0 = __builtin_bit_cast(half8, *(uint4*)&pw[0]);
        half8 pf1 = __builtin_bit_cast(half8, *(uint4*)&pw[4]);

        // ---- PV + row-sum (fp16) ----
        __builtin_amdgcn_s_setprio(1);
#pragma unroll
        for (int c = 0; c < 2; c++) {
            const half8 pf = c ? pf1 : pf0;
            lacc = mfma_f16(pf, ones, lacc);
            const int voff = ((c * 4 + quad) ^ x7) * 8;
#pragma unroll
            for (int nt2 = 0; nt2 < 4; nt2++) {
                half8 vf = __builtin_bit_cast(half8,
                    *(const short8*)&Vs[cur][(nt2 * 16 + l15) * 64 + voff]);
                oacc[nt2] = mfma_f16(pf, vf, oacc[nt2]);
            }
        }
        __builtin_amdgcn_s_setprio(0);
    }
    wait_vm0();   // drain dangling dummy prefetch before exit

    // epilogue: rows quad*4+r, cols l15
#pragma unroll
    for (int r = 0; r < 4; r++) {
        const float inv = 1.0f / lacc[r];
        const int s = qt * 128 + hh * 64 + w4 * 16 + quad * 4 + r;
#pragma unroll
        for (int nt2 = 0; nt2 < 4; nt2++)
            Oc[((size_t)(b * S_LEN + s)) * DM + h * 64 + nt2 * 16 + l15] =
                f2bf(oacc[nt2][r] * inv);
    }
}

// ---------- workspace layout (u16 elements) ----------
#define OFF_XBF   ((size_t)0)
#define OFF_WCAT  ((size_t)8388608)
#define OFF_WO    ((size_t)11534336)
#define OFF_QB    ((size_t)12582912)
#define OFF_KB    ((size_t)20971520)
#define OFF_VT    ((size_t)29360128)
#define OFF_ROPE  ((size_t)37748736)   // 65536 fp32 sin + 65536 fp32 cos = 512 KB

extern "C" void kernel_launch(void* const* d_in, const int* in_sizes, int n_in,
                              void* d_out, int out_size, void* d_ws, size_t ws_size,
                              hipStream_t stream) {
    const float* x  = (const float*)d_in[0];
    const float* Wq = (const float*)d_in[1];
    const float* Wk = (const float*)d_in[2];
    const float* Wv = (const float*)d_in[3];
    const float* Wo = (const float*)d_in[4];
    u16* ws  = (u16*)d_ws;
    u16* XBF = ws + OFF_XBF;
    u16* WCA = ws + OFF_WCAT;
    u16* WOB = ws + OFF_WO;
    u16* QB  = ws + OFF_QB;
    u16* KB  = ws + OFF_KB;
    u16* VT  = ws + OFF_VT;
    float* ropeS = (float*)(ws + OFF_ROPE);
    float* ropeC = ropeS + 65536;
    u16* AT  = XBF;   // reuse

    cvt_all<<<12544, 256, 0, stream>>>((const float4*)x, (const float4*)Wq,
                                       (const float4*)Wk, (const float4*)Wv,
                                       (const float4*)Wo,
                                       (uint2*)XBF, (uint2*)WCA, (uint2*)WOB,
                                       ropeS, ropeC);

    gemm_nt<0><<<dim3(24, 64), 256, 0, stream>>>(XBF, WCA, QB, KB, VT, nullptr,
                                                 ropeS, ropeC);
    flash_attn<<<dim3(64, 16), 512, 0, stream>>>(QB, KB, VT, AT);
    gemm_nt<1><<<dim3(8, 64), 256, 0, stream>>>(AT, WOB, nullptr, nullptr, nullptr,
                                                (float*)d_out, nullptr, nullptr);
}